// Round 15
// baseline (678.331 us; speedup 1.0000x reference)
//
#include <hip/hip_runtime.h>

typedef __bf16 bf16_t;
typedef __bf16 bf16x8 __attribute__((ext_vector_type(8)));
typedef __bf16 bf16x4_v __attribute__((ext_vector_type(4)));
typedef float f32x4 __attribute__((ext_vector_type(4)));

#define AS1 __attribute__((address_space(1)))
#define AS3 __attribute__((address_space(3)))

__device__ __forceinline__ void gload_lds16(const void* g, void* l) {
    __builtin_amdgcn_global_load_lds((AS1 void*)(void*)g, (AS3 void*)l, 16, 0, 0);
}

// ================= prep kernel (unchanged from R14) =================
__global__ void __launch_bounds__(256) prep_kernel(
    const float* __restrict__ dom_emb, const float* __restrict__ layer_pos,
    const float* __restrict__ Wi1, const float* __restrict__ bi1,
    const float* __restrict__ Wi2, const float* __restrict__ bi2,
    const float* __restrict__ Wa1, const float* __restrict__ ba1,
    const float* __restrict__ Wa2, const float* __restrict__ ba2,
    const float* __restrict__ gate_logits, const float* __restrict__ R_benefit,
    float* __restrict__ salpha,
    const float* __restrict__ s0, const float* __restrict__ s1,
    const float* __restrict__ s2, const float* __restrict__ s3,
    const float* __restrict__ s4, const float* __restrict__ s5,
    bf16_t* __restrict__ wdst,
    const float* __restrict__ B1, const float* __restrict__ B2,
    const float* __restrict__ B3, bf16_t* __restrict__ bedst,
    const float* __restrict__ x, bf16_t* __restrict__ xb)
{
    const int blk = blockIdx.x;
    const int t = threadIdx.x;
    if (blk == 0) {
        constexpr int M = 8, L = 3, E = 4, H = 64;
        __shared__ float zl[M * L];
        __shared__ float al[M * L][E];
        __shared__ float zeta_all[M][L];
        __shared__ float alpha_all[M][L][E];
        const int ml = t >> 3, js = t & 7;
        if (ml < M * L) {
            const int m = ml / L, l = ml % L;
            float zacc = 0.f;
            float aacc[E] = {0.f, 0.f, 0.f, 0.f};
            for (int jj = 0; jj < 8; ++jj) {
                const int j = js * 8 + jj;
                float hz = bi1[j], ha = ba1[j];
                for (int i = 0; i < H; ++i) {
                    const float de = dom_emb[m * H + i];
                    const float lp = layer_pos[l * H + i];
                    hz += de * Wi1[j * 2 * H + i] + lp * Wi1[j * 2 * H + H + i];
                    ha += de * Wa1[j * 2 * H + i] + lp * Wa1[j * 2 * H + H + i];
                }
                hz = fmaxf(hz, 0.f); ha = fmaxf(ha, 0.f);
                zacc += hz * Wi2[j];
                for (int e = 0; e < E; ++e) aacc[e] += ha * Wa2[e * H + j];
            }
            #pragma unroll
            for (int off = 4; off >= 1; off >>= 1) {
                zacc += __shfl_down(zacc, off, 8);
                for (int e = 0; e < E; ++e) aacc[e] += __shfl_down(aacc[e], off, 8);
            }
            if (js == 0) {
                zl[ml] = zacc + bi2[0];
                for (int e = 0; e < E; ++e) al[ml][e] = aacc[e] + ba2[e];
            }
        }
        __syncthreads();
        if (t < M) {
            const int m = t;
            float v[3] = { zl[m * L + 0], zl[m * L + 1], zl[m * L + 2] };
            int di = 0; float dv = v[0];
            for (int i = 1; i < 3; ++i) if (v[i] <= dv) { dv = v[i]; di = i; }
            float mx = -1e30f;
            for (int i = 0; i < 3; ++i) if (i != di) mx = fmaxf(mx, v[i]);
            float s = 0.f, ev[3];
            for (int i = 0; i < 3; ++i) { ev[i] = (i == di) ? 0.f : expf(v[i] - mx); s += ev[i]; }
            for (int i = 0; i < 3; ++i) zeta_all[m][i] = ev[i] / s;
            for (int l = 0; l < L; ++l) {
                float a[4];
                for (int e = 0; e < 4; ++e) a[e] = al[m * L + l][e];
                int i1 = 0;
                for (int e = 1; e < 4; ++e) if (a[e] > a[i1]) i1 = e;
                int i2 = -1;
                for (int e = 0; e < 4; ++e) { if (e == i1) continue; if (i2 < 0 || a[e] > a[i2]) i2 = e; }
                const float mx2 = fmaxf(a[i1], a[i2]);
                const float e1 = expf(a[i1] - mx2), e2 = expf(a[i2] - mx2);
                const float ss = e1 + e2;
                for (int e = 0; e < 4; ++e) alpha_all[m][l][e] = 0.f;
                alpha_all[m][l][i1] = e1 / ss;
                alpha_all[m][l][i2] = e2 / ss;
            }
        }
        __syncthreads();
        if (t < M) {
            const int m = t;
            float Rrow[8]; float rs = 0.f;
            for (int n = 0; n < M; ++n) {
                const float g = gate_logits[m * M + n];
                const float rr = log1pf(expf(g)) * R_benefit[m * M + n];
                Rrow[n] = rr; rs += rr;
            }
            rs = fmaxf(rs, 1e-12f);
            for (int l = 0; l < L; ++l) {
                float zag = 0.f, aag[4] = {0.f, 0.f, 0.f, 0.f};
                for (int n = 0; n < M; ++n) {
                    const float w = Rrow[n] / rs;
                    zag += w * zeta_all[n][l];
                    for (int e = 0; e < 4; ++e) aag[e] += w * alpha_all[n][l][e];
                }
                for (int e = 0; e < 4; ++e) salpha[(m * L + l) * 4 + e] = zag * aag[e];
            }
        }
    } else if (blk <= 6816) {
        const int i = (blk - 1) * 256 + t;
        constexpr int b0 = 1048576;
        constexpr int b1 = b0 + 524288;
        constexpr int b2 = b1 + 131072;
        constexpr int b3 = b2 + 16384;
        constexpr int b4 = b3 + 16384;
        const float* src; int rel;
        if (i < b0)      { src = s0; rel = i; }
        else if (i < b1) { src = s1; rel = i - b0; }
        else if (i < b2) { src = s2; rel = i - b1; }
        else if (i < b3) { src = s3; rel = i - b2; }
        else if (i < b4) { src = s4; rel = i - b3; }
        else             { src = s5; rel = i - b4; }
        const float4 v = ((const float4*)src)[rel];
        bf16x4_v o;
        o[0] = (__bf16)v.x; o[1] = (__bf16)v.y; o[2] = (__bf16)v.z; o[3] = (__bf16)v.w;
        ((bf16x4_v*)wdst)[i] = o;
    } else if (blk <= 7264) {
        const int idx = (blk - 6817) * 256 + t;
        constexpr int c1 = 2048 * 32, c2 = c1 + 1024 * 32;
        const float* B; int rel, Dout;
        if (idx < c1)      { B = B1; rel = idx;      Dout = 2048; }
        else if (idx < c2) { B = B2; rel = idx - c1; Dout = 1024; }
        else               { B = B3; rel = idx - c2; Dout = 512; }
        const int o = rel >> 5, c = rel & 31, e = c >> 3, r = c & 7;
        bedst[idx] = (__bf16)B[((size_t)e * Dout + o) * 8 + r];
    } else {
        const size_t i8 = ((size_t)(blk - 7265) * 256 + t) * 8;
        const float4 v0 = *(const float4*)(x + i8);
        const float4 v1 = *(const float4*)(x + i8 + 4);
        bf16x8 o;
        o[0] = (__bf16)v0.x; o[1] = (__bf16)v0.y; o[2] = (__bf16)v0.z; o[3] = (__bf16)v0.w;
        o[4] = (__bf16)v1.x; o[5] = (__bf16)v1.y; o[6] = (__bf16)v1.z; o[7] = (__bf16)v1.w;
        *(bf16x8*)(xb + i8) = o;
    }
}

// ================= 256x256 8-phase GEMM + FUSED TW + LoRA K-step =================
// R15: TW (h·Acat^T · salpha) computed in-block: each block streams its 256 rows
// x full K through LDS anyway. Per tile: +1 Acat plane stage (4KB, swizzle
// slot^=(c&7), uniform per-wave gload via dummy pad), +8 TW MFMAs per wave
// (wn<2 at P1/P4, wn>=2 at P2/P3; wave wn owns mf pair {2wn,2wn+1}).
// Ledger (re-derived, P1=3 gloads): prologue 9 + vmcnt(4); P2 vmcnt(5);
// P4 vmcnt(4); tail vmcnt(0) at P2. Finalize: scale + ds_write into parity-0
// A-plane in the tail's exact swizzled layout; lgkm drain + barrier; tail
// reads unchanged. Eliminates all 3 tw kernels + TWb traffic.
// LDS: 128KB chunks + 8KB Acat (2 parity) + 4KB dummy = 140KB (1 block/CU).

#define ACBASE  131072
#define ACDUMMY 139264

__device__ __forceinline__ void stage_chunk32(const bf16_t* g, char* chunk, int t) {
    const int row = t >> 2;
    const int sl = t & 3;
    const int src = sl ^ (((row >> 3) & 1) << 1);
    gload_lds16(g + (size_t)row * 32 + src * 8, chunk + t * 16);
}

template<int K>
__global__ void __launch_bounds__(512, 2) gemm_lora8(
    const bf16_t* __restrict__ Abuf, const bf16_t* __restrict__ Wbuf,
    const float* __restrict__ bias, const bf16_t* __restrict__ Acat,
    const bf16_t* __restrict__ Bepi, bf16_t* __restrict__ outp,
    const int N, const int nwg_n,
    const int* __restrict__ domv, const float* __restrict__ salpha, const int layer)
{
    __shared__ __align__(1024) char lds[143360];
    const int t = threadIdx.x;
    const int wid = t >> 6, lane = t & 63;
    const int wm = wid >> 2, wn = wid & 3, wnh = wn >> 1;
    const int cpx = gridDim.x >> 3;
    const int wg = (blockIdx.x & 7) * cpx + (blockIdx.x >> 3);
    const int row0 = (wg / nwg_n) * 256, col0 = (wg % nwg_n) * 256;

    const int r15 = lane & 15;
    const int swb = ((lane >> 4) ^ (((lane >> 3) & 1) << 1)) << 4;

    const char* aBase = lds + (wm << 14) + (r15 << 6) + swb;
    const char* bBase = lds + 65536 + (wnh << 14) + ((wn & 1) << 12) + (r15 << 6) + swb;
    char* const dBase = lds + t * 16;

    // Acat plane read base + per-lane swizzled slot offsets (kq0/kq1)
    const char* acBase2 = lds + ACBASE + (r15 << 7);
    const int acsw0 = (((lane >> 4)) ^ (r15 & 7)) << 4;
    const int acsw1 = ((4 + (lane >> 4)) ^ (r15 & 7)) << 4;

    // main staging source ptrs
    const int srow = t >> 2, ssl = t & 3;
    const int ssrc = ssl ^ (((srow >> 3) & 1) << 1);
    const bf16_t* sA = Abuf + (size_t)(row0 + srow) * K + ssrc * 8;
    const bf16_t* sB = Wbuf + (size_t)(col0 + srow) * K + ssrc * 8;
    constexpr size_t halfA = (size_t)128 * K;

    // Acat staging: thread tt covers plane byte tt*16 (row=tt>>3, slot=tt&7,
    // source slot = slot ^ (row&7)); threads >=256 write a dummy region so
    // every wave issues exactly 1 gload (counted-vmcnt uniformity).
    const int tt = t & 255;
    const int acrow = tt >> 3;
    const bf16_t* sAc = Acat + (size_t)acrow * K + (((tt & 7) ^ (acrow & 7)) * 8);
    char* const acD0 = (t < 256) ? (lds + ACBASE + tt * 16)        : (lds + ACDUMMY + tt * 16);
    char* const acD1 = (t < 256) ? (lds + ACBASE + 4096 + tt * 16) : (lds + ACDUMMY + tt * 16);

    f32x4 acc[8][4] = {};
    f32x4 twacc[2][2] = {};
    bf16x8 aF[4], bF[4], acF[2];

    #define RD_A(P, KQ, MB) do { _Pragma("unroll") for (int i_ = 0; i_ < 4; ++i_) \
        aF[i_] = *(const bf16x8*)(aBase + (P)*32768 + (KQ)*8192 + ((MB)+i_)*1024); } while (0)
    #define RD_B(P, KQ) do { _Pragma("unroll") for (int n_ = 0; n_ < 4; ++n_) \
        bF[n_] = *(const bf16x8*)(bBase + (P)*32768 + (KQ)*8192 + n_*1024); } while (0)
    #define RD_AC(P, KQ) do { _Pragma("unroll") for (int n_ = 0; n_ < 2; ++n_) \
        acF[n_] = *(const bf16x8*)(acBase2 + (P)*4096 + n_*2048 + ((KQ) ? acsw1 : acsw0)); } while (0)
    #define TW_MM() do { _Pragma("unroll") for (int mp_ = 0; mp_ < 2; ++mp_) \
        _Pragma("unroll") for (int n_ = 0; n_ < 2; ++n_) \
        twacc[mp_][n_] = __builtin_amdgcn_mfma_f32_16x16x32_bf16(aF[2*(wn&1)+mp_], acF[n_], twacc[mp_][n_], 0, 0, 0); } while (0)

    auto mfma16 = [&](int mbase) {
        __builtin_amdgcn_s_setprio(1);
        #pragma unroll
        for (int mf = 0; mf < 4; ++mf)
            #pragma unroll
            for (int nf = 0; nf < 4; ++nf)
                acc[mbase + mf][nf] =
                    __builtin_amdgcn_mfma_f32_16x16x32_bf16(aF[mf], bF[nf], acc[mbase + mf][nf], 0, 0, 0);
        __builtin_amdgcn_s_setprio(0);
    };
    #define BAR() __builtin_amdgcn_s_barrier()

    constexpr int NT = K >> 6;   // even, >= 16

    // Prologue: T0 {A.k0 x2, Acat, B.k0 x2, A.k1 x2, B.k1 x2} = 9 loads.
    // vmcnt(4) -> first 5 (A.k0, Acat, B.k0) landed.
    gload_lds16(sA,              dBase + 0);
    gload_lds16(sA + halfA,      dBase + 16384);
    gload_lds16(sAc,             acD0);
    gload_lds16(sB,              dBase + 65536);
    gload_lds16(sB + halfA,      dBase + 65536 + 16384);
    gload_lds16(sA + 32,         dBase + 8192);
    gload_lds16(sA + halfA + 32, dBase + 24576);
    gload_lds16(sB + 32,         dBase + 65536 + 8192);
    gload_lds16(sB + halfA + 32, dBase + 65536 + 24576);
    asm volatile("s_waitcnt vmcnt(4)" ::: "memory");
    __builtin_amdgcn_s_barrier();

    const bf16_t* pA0 = sA + 64;
    const bf16_t* pA1 = sA + halfA + 64;
    const bf16_t* pB0 = sB + 64;
    const bf16_t* pB1 = sB + halfA + 64;
    const bf16_t* pAc = sAc + 64;

    #define TILE(P, MORE, TOFF) do {                                            \
        RD_A(P, 0, 0);                                                           \
        RD_B(P, 0);                                                              \
        if (wn < 2) RD_AC(P, 0);                                                 \
        if (MORE) { gload_lds16(pA0 + (TOFF), dBase + ((P)^1)*32768 + 0);        \
                    gload_lds16(pA1 + (TOFF), dBase + ((P)^1)*32768 + 16384);    \
                    gload_lds16(pAc + (TOFF), (P) ? acD0 : acD1); }              \
        BAR();                                                                   \
        mfma16(0);                                                               \
        if (wn < 2) TW_MM();                                                     \
        RD_A(P, 0, 4);                                                           \
        if (wn >= 2) RD_AC(P, 0);                                                \
        if (MORE) {                                                              \
            gload_lds16(pB0 + (TOFF), dBase + 65536 + ((P)^1)*32768 + 0);        \
            gload_lds16(pB1 + (TOFF), dBase + 65536 + ((P)^1)*32768 + 16384);    \
            asm volatile("s_waitcnt vmcnt(5)" ::: "memory");                     \
        } else {                                                                 \
            asm volatile("s_waitcnt vmcnt(0)" ::: "memory");                     \
        }                                                                        \
        BAR();                                                                   \
        mfma16(4);                                                               \
        if (wn >= 2) TW_MM();                                                    \
        RD_A(P, 1, 4);                                                           \
        RD_B(P, 1);                                                              \
        if (wn >= 2) RD_AC(P, 1);                                                \
        if (MORE) { gload_lds16(pA0 + (TOFF) + 32, dBase + ((P)^1)*32768 + 8192);  \
                    gload_lds16(pA1 + (TOFF) + 32, dBase + ((P)^1)*32768 + 24576);} \
        BAR();                                                                   \
        mfma16(4);                                                               \
        if (wn >= 2) TW_MM();                                                    \
        RD_A(P, 1, 0);                                                           \
        if (wn < 2) RD_AC(P, 1);                                                 \
        if (MORE) {                                                              \
            gload_lds16(pB0 + (TOFF) + 32, dBase + 65536 + ((P)^1)*32768 + 8192);  \
            gload_lds16(pB1 + (TOFF) + 32, dBase + 65536 + ((P)^1)*32768 + 24576); \
            asm volatile("s_waitcnt vmcnt(4)" ::: "memory");                     \
        }                                                                        \
        BAR();                                                                   \
        mfma16(0);                                                               \
        if (wn < 2) TW_MM();                                                     \
    } while (0)

    #pragma unroll 1
    for (int T = 0; T < NT - 2; T += 2) {
        TILE(0, true, 0);
        TILE(1, true, 64);
        pA0 += 128; pA1 += 128; pB0 += 128; pB1 += 128; pAc += 128;
    }
    TILE(0, true, 0);
    TILE(1, false, 64);

    // ---- TW finalize + LoRA tail ----
    {
        asm volatile("" ::: "memory");
        __builtin_amdgcn_s_barrier();   // all main-loop LDS reads complete
        // Bepi staging overlaps TW finalize (independent)
        stage_chunk32(Bepi + (size_t)col0 * 32,         lds + 65536,         t);
        stage_chunk32(Bepi + (size_t)(col0 + 128) * 32, lds + 65536 + 16384, t);
        // scale TW and write into parity-0 A-plane (tail's swizzled layout)
        const int i16 = lane >> 4;
        #pragma unroll
        for (int mp_ = 0; mp_ < 2; ++mp_) {
            const int mfg = 2 * wn + mp_;
            #pragma unroll
            for (int i_ = 0; i_ < 4; ++i_) {
                const int rl = mfg * 16 + i16 * 4 + i_;          // 0..127
                const int d = domv[row0 + wm * 128 + rl];
                const float* sa = salpha + (d * 3 + layer) * 4;
                #pragma unroll
                for (int n_ = 0; n_ < 2; ++n_) {
                    const int c = n_ * 16 + r15;
                    const float s = sa[n_ * 2 + (r15 >> 3)];
                    const float v = twacc[mp_][n_][i_] * s;
                    *(bf16_t*)(lds + (wm << 14) + rl * 64 +
                               (((c >> 3) ^ (((rl >> 3) & 1) << 1)) << 4) + ((c & 7) << 1)) = (__bf16)v;
                }
            }
        }
        asm volatile("s_waitcnt vmcnt(0) lgkmcnt(0)" ::: "memory");
        __builtin_amdgcn_sched_barrier(0);
        __builtin_amdgcn_s_barrier();
        RD_B(0, 0);
        RD_A(0, 0, 0);
        mfma16(0);
        RD_A(0, 0, 4);
        mfma16(4);
    }

    // Epilogue: per-wave LDS bounce -> full-128B-line stores (R13-verified).
    __builtin_amdgcn_s_barrier();
    {
        char* eb = lds + wid * 2048;
        const int rloc = (lane >> 4) * 4;
        const int g = lane >> 4;
        const int orow0 = row0 + wm * 128;
        const int ocol0 = col0 + wn * 64;
        float bcol[4];
        #pragma unroll
        for (int nf = 0; nf < 4; ++nf) bcol[nf] = bias[ocol0 + nf * 16 + r15];
        const int rdrow = lane >> 3;
        const int rdcolb = (lane & 7) * 16;
        const int rdoff0 = rdrow * 128 + (rdcolb ^ ((rdrow >> 2) << 5));
        const int rdoff1 = (rdrow + 8) * 128 + (rdcolb ^ (((rdrow + 8) >> 2) << 5));
        bf16_t* outbase = outp + (size_t)ocol0 + (lane & 7) * 8;
        #pragma unroll
        for (int mf = 0; mf < 8; ++mf) {
            #pragma unroll
            for (int i = 0; i < 4; ++i) {
                const int r = rloc + i;
                #pragma unroll
                for (int nf = 0; nf < 4; ++nf) {
                    const float v = fmaxf(acc[mf][nf][i] + bcol[nf], 0.f);
                    *(bf16_t*)(eb + r * 128 + ((nf ^ g) * 32 + r15 * 2)) = (__bf16)v;
                }
            }
            __builtin_amdgcn_sched_barrier(0);
            asm volatile("" ::: "memory");
            const bf16x8 v0 = *(const bf16x8*)(eb + rdoff0);
            const bf16x8 v1 = *(const bf16x8*)(eb + rdoff1);
            asm volatile("" ::: "memory");
            __builtin_amdgcn_sched_barrier(0);
            *(bf16x8*)(outbase + (size_t)(orow0 + mf * 16 + rdrow) * N) = v0;
            *(bf16x8*)(outbase + (size_t)(orow0 + mf * 16 + 8 + rdrow) * N) = v1;
        }
    }
    #undef TILE
    #undef RD_A
    #undef RD_B
    #undef RD_AC
    #undef TW_MM
    #undef BAR
}

// ---------------- 128x128 GEMM (layer 3) with fused TW ----------------
#define BM 128
#define BN 128
#define BK 32

template<bool OUT_F32, int K>
__global__ void __launch_bounds__(256) gemm_lora(
    const bf16_t* __restrict__ Abuf, const bf16_t* __restrict__ Wbuf,
    const float* __restrict__ bias, const bf16_t* __restrict__ Acat,
    const bf16_t* __restrict__ Bepi, void* __restrict__ outp,
    const int N,
    const int* __restrict__ domv, const float* __restrict__ salpha)
{
    __shared__ bf16_t lA[BM * BK];
    __shared__ bf16_t lB[BN * BK];
    __shared__ bf16_t lAc[32 * BK];
    const int t = threadIdx.x;
    const int row0 = blockIdx.y * BM;
    const int col0 = blockIdx.x * BN;
    const int wid = t >> 6, lane = t & 63;
    const int wr = wid >> 1, wc = wid & 1;
    const int ln15 = lane & 15, kg = (lane >> 4) * 8;
    const int srow = t >> 2, sg8 = (t & 3) * 8;
    const bf16_t* gA = Abuf + (size_t)(row0 + srow) * K + sg8;
    const bf16_t* gB = Wbuf + (size_t)(col0 + srow) * K + sg8;
    bf16_t* ldA  = &lA[t * 8];
    bf16_t* ldA2 = &lA[2048 + t * 8];
    bf16_t* ldB  = &lB[t * 8];
    bf16_t* ldB2 = &lB[2048 + t * 8];
    f32x4 acc[4][4] = {};
    f32x4 twacc[4] = {};
    bf16x8 af[4], bfr[4];
    const int aoff = (wr * 64 + ln15) * BK + kg;
    const int boff = (wc * 64 + ln15) * BK + kg;

    auto compute_tile = [&]() {
        #pragma unroll
        for (int m = 0; m < 4; ++m) af[m] = *(const bf16x8*)&lA[aoff + m * 16 * BK];
        #pragma unroll
        for (int n = 0; n < 4; ++n) bfr[n] = *(const bf16x8*)&lB[boff + n * 16 * BK];
        #pragma unroll
        for (int m = 0; m < 4; ++m)
            #pragma unroll
            for (int n = 0; n < 4; ++n)
                acc[m][n] = __builtin_amdgcn_mfma_f32_16x16x32_bf16(af[m], bfr[n], acc[m][n], 0, 0, 0);
    };

    constexpr size_t half = (size_t)64 * K;
    constexpr int nk = K / BK;
    #pragma unroll 1
    for (int kt = 0; kt < nk; ++kt) {
        gload_lds16(gA + kt * BK, ldA);
        gload_lds16(gA + half + kt * BK, ldA2);
        gload_lds16(gB + kt * BK, ldB);
        gload_lds16(gB + half + kt * BK, ldB2);
        if (t < 128)
            gload_lds16(Acat + (size_t)(t >> 2) * K + kt * BK + (t & 3) * 8, (char*)lAc + t * 16);
        __syncthreads();
        compute_tile();
        // fused TW: rows wr-half x cols (wc 16-half), 4 MFMAs/step
        {
            const bf16x8 acatF = *(const bf16x8*)&lAc[(wc * 16 + ln15) * BK + kg];
            #pragma unroll
            for (int m = 0; m < 4; ++m)
                twacc[m] = __builtin_amdgcn_mfma_f32_16x16x32_bf16(af[m], acatF, twacc[m], 0, 0, 0);
        }
        __syncthreads();
    }
    // TW finalize: scale and write into lA linear [128][32]
    {
        const int i16 = lane >> 4;
        #pragma unroll
        for (int m = 0; m < 4; ++m) {
            #pragma unroll
            for (int i = 0; i < 4; ++i) {
                const int r = wr * 64 + m * 16 + i16 * 4 + i;
                const int d = domv[row0 + r];
                const int c = wc * 16 + ln15;
                const float s = salpha[(d * 3 + 2) * 4 + wc * 2 + (ln15 >> 3)];
                lA[r * BK + c] = (__bf16)(twacc[m][i] * s);
            }
        }
    }
    gload_lds16(Bepi + (size_t)(col0 + srow) * 32 + sg8, ldB);
    gload_lds16(Bepi + (size_t)(col0 + 64 + srow) * 32 + sg8, ldB2);
    __syncthreads();
    compute_tile();

    const int orow = row0 + wr * 64 + (lane >> 4) * 4;
    const int ocol = col0 + wc * 64 + ln15;
    #pragma unroll
    for (int n = 0; n < 4; ++n) {
        const int col = ocol + n * 16;
        const float bn = bias[col];
        #pragma unroll
        for (int m = 0; m < 4; ++m) {
            const int rbase = orow + m * 16;
            #pragma unroll
            for (int i = 0; i < 4; ++i) {
                const float v = fmaxf(acc[m][n][i] + bn, 0.f);
                if constexpr (OUT_F32)
                    ((float*)outp)[(size_t)(rbase + i) * N + col] = v;
                else
                    ((bf16_t*)outp)[(size_t)(rbase + i) * N + col] = (__bf16)v;
            }
        }
    }
}

extern "C" void kernel_launch(void* const* d_in, const int* in_sizes, int n_in,
                              void* d_out, int out_size, void* d_ws, size_t ws_size,
                              hipStream_t stream)
{
    const float* x    = (const float*)d_in[0];
    const int*   dom  = (const int*)d_in[1];
    const float* W1   = (const float*)d_in[2];  const float* b1  = (const float*)d_in[3];
    const float* W2   = (const float*)d_in[4];  const float* b2  = (const float*)d_in[5];
    const float* W3   = (const float*)d_in[6];  const float* b3  = (const float*)d_in[7];
    const float* A1   = (const float*)d_in[8];  const float* B1  = (const float*)d_in[9];
    const float* A2   = (const float*)d_in[10]; const float* B2  = (const float*)d_in[11];
    const float* A3   = (const float*)d_in[12]; const float* B3  = (const float*)d_in[13];
    const float* dome = (const float*)d_in[14]; const float* lpos = (const float*)d_in[15];
    const float* Wi1  = (const float*)d_in[16]; const float* bi1 = (const float*)d_in[17];
    const float* Wi2  = (const float*)d_in[18]; const float* bi2 = (const float*)d_in[19];
    const float* Wa1  = (const float*)d_in[20]; const float* ba1 = (const float*)d_in[21];
    const float* Wa2  = (const float*)d_in[22]; const float* ba2 = (const float*)d_in[23];
    const float* gate = (const float*)d_in[24]; const float* Rb  = (const float*)d_in[25];
    (void)in_sizes; (void)n_in; (void)out_size; (void)ws_size;

    constexpr int Bsz = 16384, D0 = 2048, D1 = 2048, D2 = 1024, D3 = 512;

    char* ws = (char*)d_ws;
    size_t off = 0;
    auto alloc = [&](size_t bytes) -> void* {
        void* p = ws + off;
        off = (off + bytes + 255) & ~(size_t)255;
        return p;
    };
    float*  salpha = (float*) alloc(8 * 3 * 4 * sizeof(float));
    bf16_t* W1b = (bf16_t*)alloc((size_t)D1 * D0 * 2);
    bf16_t* W2b = (bf16_t*)alloc((size_t)D2 * D1 * 2);
    bf16_t* W3b = (bf16_t*)alloc((size_t)D3 * D2 * 2);
    bf16_t* Ac1 = (bf16_t*)alloc((size_t)32 * D0 * 2);
    bf16_t* Ac2 = (bf16_t*)alloc((size_t)32 * D1 * 2);
    bf16_t* Ac3 = (bf16_t*)alloc((size_t)32 * D2 * 2);
    bf16_t* Be1 = (bf16_t*)alloc((size_t)D1 * 32 * 2);
    bf16_t* Be2 = (bf16_t*)alloc((size_t)D2 * 32 * 2);
    bf16_t* Be3 = (bf16_t*)alloc((size_t)D3 * 32 * 2);
    bf16_t* xb  = (bf16_t*)alloc((size_t)Bsz * D0 * 2);
    bf16_t* h1b = (bf16_t*)alloc((size_t)Bsz * D1 * 2);
    bf16_t* h2b = xb;  // xb dead after layer-1 GEMM

    // prep: routing (1) + W/A cvt (6816) + Bepi (448) + x cast (16384)
    prep_kernel<<<23649, 256, 0, stream>>>(
        dome, lpos, Wi1, bi1, Wi2, bi2, Wa1, ba1, Wa2, ba2, gate, Rb, salpha,
        W1, W2, W3, A1, A2, A3, W1b,
        B1, B2, B3, Be1,
        x, xb);

    // layer 1: K = D0 = 2048, N = D1 = 2048 (TW fused)
    gemm_lora8<2048><<<(Bsz / 256) * (D1 / 256), 512, 0, stream>>>(
        xb, W1b, b1, Ac1, Be1, h1b, D1, D1 / 256, dom, salpha, 0);
    // layer 2: K = D1 = 2048, N = D2 = 1024 (TW fused)
    gemm_lora8<2048><<<(Bsz / 256) * (D2 / 256), 512, 0, stream>>>(
        h1b, W2b, b2, Ac2, Be2, h2b, D2, D2 / 256, dom, salpha, 1);
    // layer 3: K = D2 = 1024 (f32 out, 128^2 kernel, TW fused)
    gemm_lora<true, 1024><<<dim3(D3 / BN, Bsz / BM), 256, 0, stream>>>(
        h2b, W3b, b3, Ac3, Be3, d_out, D3, dom, salpha);
}

// Round 16
// 346.328 us; speedup vs baseline: 1.9586x; 1.9586x over previous
//
#include <hip/hip_runtime.h>

typedef __bf16 bf16_t;
typedef __bf16 bf16x8 __attribute__((ext_vector_type(8)));
typedef __bf16 bf16x4_v __attribute__((ext_vector_type(4)));
typedef float f32x4 __attribute__((ext_vector_type(4)));

#define AS1 __attribute__((address_space(1)))
#define AS3 __attribute__((address_space(3)))

__device__ __forceinline__ void gload_lds16(const void* g, void* l) {
    __builtin_amdgcn_global_load_lds((AS1 void*)(void*)g, (AS3 void*)l, 16, 0, 0);
}

// ================= prep kernel (R14-verified) =================
__global__ void __launch_bounds__(256) prep_kernel(
    const float* __restrict__ dom_emb, const float* __restrict__ layer_pos,
    const float* __restrict__ Wi1, const float* __restrict__ bi1,
    const float* __restrict__ Wi2, const float* __restrict__ bi2,
    const float* __restrict__ Wa1, const float* __restrict__ ba1,
    const float* __restrict__ Wa2, const float* __restrict__ ba2,
    const float* __restrict__ gate_logits, const float* __restrict__ R_benefit,
    float* __restrict__ salpha,
    const float* __restrict__ s0, const float* __restrict__ s1,
    const float* __restrict__ s2, const float* __restrict__ s3,
    const float* __restrict__ s4, const float* __restrict__ s5,
    bf16_t* __restrict__ wdst,
    const float* __restrict__ B1, const float* __restrict__ B2,
    const float* __restrict__ B3, bf16_t* __restrict__ bedst,
    const float* __restrict__ x, bf16_t* __restrict__ xb)
{
    const int blk = blockIdx.x;
    const int t = threadIdx.x;
    if (blk == 0) {
        constexpr int M = 8, L = 3, E = 4, H = 64;
        __shared__ float zl[M * L];
        __shared__ float al[M * L][E];
        __shared__ float zeta_all[M][L];
        __shared__ float alpha_all[M][L][E];
        const int ml = t >> 3, js = t & 7;
        if (ml < M * L) {
            const int m = ml / L, l = ml % L;
            float zacc = 0.f;
            float aacc[E] = {0.f, 0.f, 0.f, 0.f};
            for (int jj = 0; jj < 8; ++jj) {
                const int j = js * 8 + jj;
                float hz = bi1[j], ha = ba1[j];
                for (int i = 0; i < H; ++i) {
                    const float de = dom_emb[m * H + i];
                    const float lp = layer_pos[l * H + i];
                    hz += de * Wi1[j * 2 * H + i] + lp * Wi1[j * 2 * H + H + i];
                    ha += de * Wa1[j * 2 * H + i] + lp * Wa1[j * 2 * H + H + i];
                }
                hz = fmaxf(hz, 0.f); ha = fmaxf(ha, 0.f);
                zacc += hz * Wi2[j];
                for (int e = 0; e < E; ++e) aacc[e] += ha * Wa2[e * H + j];
            }
            #pragma unroll
            for (int off = 4; off >= 1; off >>= 1) {
                zacc += __shfl_down(zacc, off, 8);
                for (int e = 0; e < E; ++e) aacc[e] += __shfl_down(aacc[e], off, 8);
            }
            if (js == 0) {
                zl[ml] = zacc + bi2[0];
                for (int e = 0; e < E; ++e) al[ml][e] = aacc[e] + ba2[e];
            }
        }
        __syncthreads();
        if (t < M) {
            const int m = t;
            float v[3] = { zl[m * L + 0], zl[m * L + 1], zl[m * L + 2] };
            int di = 0; float dv = v[0];
            for (int i = 1; i < 3; ++i) if (v[i] <= dv) { dv = v[i]; di = i; }
            float mx = -1e30f;
            for (int i = 0; i < 3; ++i) if (i != di) mx = fmaxf(mx, v[i]);
            float s = 0.f, ev[3];
            for (int i = 0; i < 3; ++i) { ev[i] = (i == di) ? 0.f : expf(v[i] - mx); s += ev[i]; }
            for (int i = 0; i < 3; ++i) zeta_all[m][i] = ev[i] / s;
            for (int l = 0; l < L; ++l) {
                float a[4];
                for (int e = 0; e < 4; ++e) a[e] = al[m * L + l][e];
                int i1 = 0;
                for (int e = 1; e < 4; ++e) if (a[e] > a[i1]) i1 = e;
                int i2 = -1;
                for (int e = 0; e < 4; ++e) { if (e == i1) continue; if (i2 < 0 || a[e] > a[i2]) i2 = e; }
                const float mx2 = fmaxf(a[i1], a[i2]);
                const float e1 = expf(a[i1] - mx2), e2 = expf(a[i2] - mx2);
                const float ss = e1 + e2;
                for (int e = 0; e < 4; ++e) alpha_all[m][l][e] = 0.f;
                alpha_all[m][l][i1] = e1 / ss;
                alpha_all[m][l][i2] = e2 / ss;
            }
        }
        __syncthreads();
        if (t < M) {
            const int m = t;
            float Rrow[8]; float rs = 0.f;
            for (int n = 0; n < M; ++n) {
                const float g = gate_logits[m * M + n];
                const float rr = log1pf(expf(g)) * R_benefit[m * M + n];
                Rrow[n] = rr; rs += rr;
            }
            rs = fmaxf(rs, 1e-12f);
            for (int l = 0; l < L; ++l) {
                float zag = 0.f, aag[4] = {0.f, 0.f, 0.f, 0.f};
                for (int n = 0; n < M; ++n) {
                    const float w = Rrow[n] / rs;
                    zag += w * zeta_all[n][l];
                    for (int e = 0; e < 4; ++e) aag[e] += w * alpha_all[n][l][e];
                }
                for (int e = 0; e < 4; ++e) salpha[(m * L + l) * 4 + e] = zag * aag[e];
            }
        }
    } else if (blk <= 6816) {
        const int i = (blk - 1) * 256 + t;
        constexpr int b0 = 1048576;
        constexpr int b1 = b0 + 524288;
        constexpr int b2 = b1 + 131072;
        constexpr int b3 = b2 + 16384;
        constexpr int b4 = b3 + 16384;
        const float* src; int rel;
        if (i < b0)      { src = s0; rel = i; }
        else if (i < b1) { src = s1; rel = i - b0; }
        else if (i < b2) { src = s2; rel = i - b1; }
        else if (i < b3) { src = s3; rel = i - b2; }
        else if (i < b4) { src = s4; rel = i - b3; }
        else             { src = s5; rel = i - b4; }
        const float4 v = ((const float4*)src)[rel];
        bf16x4_v o;
        o[0] = (__bf16)v.x; o[1] = (__bf16)v.y; o[2] = (__bf16)v.z; o[3] = (__bf16)v.w;
        ((bf16x4_v*)wdst)[i] = o;
    } else if (blk <= 7264) {
        const int idx = (blk - 6817) * 256 + t;
        constexpr int c1 = 2048 * 32, c2 = c1 + 1024 * 32;
        const float* B; int rel, Dout;
        if (idx < c1)      { B = B1; rel = idx;      Dout = 2048; }
        else if (idx < c2) { B = B2; rel = idx - c1; Dout = 1024; }
        else               { B = B3; rel = idx - c2; Dout = 512; }
        const int o = rel >> 5, c = rel & 31, e = c >> 3, r = c & 7;
        bedst[idx] = (__bf16)B[((size_t)e * Dout + o) * 8 + r];
    } else {
        const size_t i8 = ((size_t)(blk - 7265) * 256 + t) * 8;
        const float4 v0 = *(const float4*)(x + i8);
        const float4 v1 = *(const float4*)(x + i8 + 4);
        bf16x8 o;
        o[0] = (__bf16)v0.x; o[1] = (__bf16)v0.y; o[2] = (__bf16)v0.z; o[3] = (__bf16)v0.w;
        o[4] = (__bf16)v1.x; o[5] = (__bf16)v1.y; o[6] = (__bf16)v1.z; o[7] = (__bf16)v1.w;
        *(bf16x8*)(xb + i8) = o;
    }
}

// ---------------- tw_kernel (R14-verified): 8 waves, K-split halves + LDS reduce
__global__ void __launch_bounds__(512) tw_kernel(
    const bf16_t* __restrict__ hin,
    const bf16_t* __restrict__ Acat, const float* __restrict__ salpha,
    const int* __restrict__ dom, const int layer, const int K,
    bf16_t* __restrict__ TWb)
{
    __shared__ float red[4 * 64 * 8];
    const int t = threadIdx.x, wid = t >> 6, lane = t & 63;
    const int g = wid & 3, h = wid >> 2;
    const int rb = blockIdx.x * 64 + g * 16;
    const int ln15 = lane & 15, kg = (lane >> 4) * 8;
    const int row = rb + ln15;
    const int Kh = K >> 1, Kq = K >> 2;
    const int base = h * Kh;
    f32x4 a0l = {0.f,0.f,0.f,0.f}, a1l = {0.f,0.f,0.f,0.f};
    f32x4 a0h = {0.f,0.f,0.f,0.f}, a1h = {0.f,0.f,0.f,0.f};
    const bf16_t* ph  = hin + (size_t)row * K + base + kg;
    const bf16_t* pa0 = Acat + (size_t)ln15 * K + base + kg;
    const bf16_t* pa1 = pa0 + (size_t)16 * K;
    for (int k0 = 0; k0 < Kq; k0 += 32) {
        const bf16x8 al  = *(const bf16x8*)(ph + k0);
        const bf16x8 ah  = *(const bf16x8*)(ph + Kq + k0);
        const bf16x8 b0l = *(const bf16x8*)(pa0 + k0);
        const bf16x8 b1l = *(const bf16x8*)(pa1 + k0);
        const bf16x8 b0h = *(const bf16x8*)(pa0 + Kq + k0);
        const bf16x8 b1h = *(const bf16x8*)(pa1 + Kq + k0);
        a0l = __builtin_amdgcn_mfma_f32_16x16x32_bf16(al, b0l, a0l, 0, 0, 0);
        a1l = __builtin_amdgcn_mfma_f32_16x16x32_bf16(al, b1l, a1l, 0, 0, 0);
        a0h = __builtin_amdgcn_mfma_f32_16x16x32_bf16(ah, b0h, a0h, 0, 0, 0);
        a1h = __builtin_amdgcn_mfma_f32_16x16x32_bf16(ah, b1h, a1h, 0, 0, 0);
    }
    f32x4 acc0 = a0l + a0h;
    f32x4 acc1 = a1l + a1h;
    float* slot = red + ((g * 64 + lane) << 3);
    if (h == 1) {
        *(f32x4*)slot = acc0;
        *(f32x4*)(slot + 4) = acc1;
    }
    __syncthreads();
    if (h == 0) {
        acc0 += *(const f32x4*)slot;
        acc1 += *(const f32x4*)(slot + 4);
        const int rbase = rb + (lane >> 4) * 4;
        #pragma unroll
        for (int i = 0; i < 4; ++i) {
            const int r2 = rbase + i;
            const int d = dom[r2];
            const float* sa = salpha + (d * 3 + layer) * 4;
            const float s0 = sa[ln15 >> 3];
            const float s1 = sa[2 + (ln15 >> 3)];
            TWb[(size_t)r2 * 32 + ln15]      = (__bf16)(acc0[i] * s0);
            TWb[(size_t)r2 * 32 + 16 + ln15] = (__bf16)(acc1[i] * s1);
        }
    }
}

// ================= 256x256 8-phase GEMM + LoRA K-step (R14-verified, NO fusion;
// R15's in-loop TW fusion caused register spill: VGPR 100->128, +23MB scratch
// writes, MfmaUtil 56->16. This kernel is at the register ceiling.) ============

__device__ __forceinline__ void stage_chunk32(const bf16_t* g, char* chunk, int t) {
    const int row = t >> 2;
    const int sl = t & 3;
    const int src = sl ^ (((row >> 3) & 1) << 1);
    gload_lds16(g + (size_t)row * 32 + src * 8, chunk + t * 16);
}

template<int K>
__global__ void __launch_bounds__(512, 2) gemm_lora8(
    const bf16_t* __restrict__ Abuf, const bf16_t* __restrict__ Wbuf,
    const float* __restrict__ bias, const bf16_t* __restrict__ TWb,
    const bf16_t* __restrict__ Bepi, bf16_t* __restrict__ outp,
    const int N, const int nwg_n)
{
    __shared__ __align__(1024) char lds[131072];
    const int t = threadIdx.x;
    const int wid = t >> 6, lane = t & 63;
    const int wm = wid >> 2, wn = wid & 3, wnh = wn >> 1;
    const int cpx = gridDim.x >> 3;
    const int wg = (blockIdx.x & 7) * cpx + (blockIdx.x >> 3);
    const int row0 = (wg / nwg_n) * 256, col0 = (wg % nwg_n) * 256;

    const int r15 = lane & 15;
    const int swb = ((lane >> 4) ^ (((lane >> 3) & 1) << 1)) << 4;

    const char* aBase = lds + (wm << 14) + (r15 << 6) + swb;
    const char* bBase = lds + 65536 + (wnh << 14) + ((wn & 1) << 12) + (r15 << 6) + swb;
    char* const dBase = lds + t * 16;

    const int srow = t >> 2, ssl = t & 3;
    const int ssrc = ssl ^ (((srow >> 3) & 1) << 1);
    const bf16_t* sA = Abuf + (size_t)(row0 + srow) * K + ssrc * 8;
    const bf16_t* sB = Wbuf + (size_t)(col0 + srow) * K + ssrc * 8;
    constexpr size_t halfA = (size_t)128 * K;

    f32x4 acc[8][4] = {};
    bf16x8 aF[4], bF[4];

    #define RD_A(P, KQ, MB) do { _Pragma("unroll") for (int i_ = 0; i_ < 4; ++i_) \
        aF[i_] = *(const bf16x8*)(aBase + (P)*32768 + (KQ)*8192 + ((MB)+i_)*1024); } while (0)
    #define RD_B(P, KQ) do { _Pragma("unroll") for (int n_ = 0; n_ < 4; ++n_) \
        bF[n_] = *(const bf16x8*)(bBase + (P)*32768 + (KQ)*8192 + n_*1024); } while (0)

    auto mfma16 = [&](int mbase) {
        __builtin_amdgcn_s_setprio(1);
        #pragma unroll
        for (int mf = 0; mf < 4; ++mf)
            #pragma unroll
            for (int nf = 0; nf < 4; ++nf)
                acc[mbase + mf][nf] =
                    __builtin_amdgcn_mfma_f32_16x16x32_bf16(aF[mf], bF[nf], acc[mbase + mf][nf], 0, 0, 0);
        __builtin_amdgcn_s_setprio(0);
    };
    #define BAR() __builtin_amdgcn_s_barrier()

    constexpr int NT = K >> 6;

    gload_lds16(sA,              dBase + 0);
    gload_lds16(sA + halfA,      dBase + 16384);
    gload_lds16(sB,              dBase + 65536);
    gload_lds16(sB + halfA,      dBase + 65536 + 16384);
    gload_lds16(sA + 32,         dBase + 8192);
    gload_lds16(sA + halfA + 32, dBase + 24576);
    gload_lds16(sB + 32,         dBase + 65536 + 8192);
    gload_lds16(sB + halfA + 32, dBase + 65536 + 24576);
    asm volatile("s_waitcnt vmcnt(4)" ::: "memory");
    __builtin_amdgcn_s_barrier();

    const bf16_t* pA0 = sA + 64;
    const bf16_t* pA1 = sA + halfA + 64;
    const bf16_t* pB0 = sB + 64;
    const bf16_t* pB1 = sB + halfA + 64;

    #define TILE(P, MORE, TOFF) do {                                            \
        RD_A(P, 0, 0);                                                           \
        RD_B(P, 0);                                                              \
        if (MORE) { gload_lds16(pA0 + (TOFF), dBase + ((P)^1)*32768 + 0);        \
                    gload_lds16(pA1 + (TOFF), dBase + ((P)^1)*32768 + 16384); }  \
        BAR();                                                                   \
        mfma16(0);                                                               \
        RD_A(P, 0, 4);                                                           \
        if (MORE) {                                                              \
            gload_lds16(pB0 + (TOFF), dBase + 65536 + ((P)^1)*32768 + 0);        \
            gload_lds16(pB1 + (TOFF), dBase + 65536 + ((P)^1)*32768 + 16384);    \
            asm volatile("s_waitcnt vmcnt(4)" ::: "memory");                     \
        } else {                                                                 \
            asm volatile("s_waitcnt vmcnt(0)" ::: "memory");                     \
        }                                                                        \
        BAR();                                                                   \
        mfma16(4);                                                               \
        RD_A(P, 1, 4);                                                           \
        RD_B(P, 1);                                                              \
        if (MORE) { gload_lds16(pA0 + (TOFF) + 32, dBase + ((P)^1)*32768 + 8192);  \
                    gload_lds16(pA1 + (TOFF) + 32, dBase + ((P)^1)*32768 + 24576);} \
        BAR();                                                                   \
        mfma16(4);                                                               \
        RD_A(P, 1, 0);                                                           \
        if (MORE) {                                                              \
            gload_lds16(pB0 + (TOFF) + 32, dBase + 65536 + ((P)^1)*32768 + 8192);  \
            gload_lds16(pB1 + (TOFF) + 32, dBase + 65536 + ((P)^1)*32768 + 24576); \
            asm volatile("s_waitcnt vmcnt(4)" ::: "memory");                     \
        }                                                                        \
        BAR();                                                                   \
        mfma16(0);                                                               \
    } while (0)

    #pragma unroll 1
    for (int T = 0; T < NT - 2; T += 2) {
        TILE(0, true, 0);
        TILE(1, true, 64);
        pA0 += 128; pA1 += 128; pB0 += 128; pB1 += 128;
    }
    TILE(0, true, 0);
    TILE(1, false, 64);

    {
        __builtin_amdgcn_s_barrier();
        stage_chunk32(TWb + (size_t)row0 * 32,          lds + 0,             t);
        stage_chunk32(TWb + (size_t)(row0 + 128) * 32,  lds + 16384,         t);
        stage_chunk32(Bepi + (size_t)col0 * 32,         lds + 65536,         t);
        stage_chunk32(Bepi + (size_t)(col0 + 128) * 32, lds + 65536 + 16384, t);
        asm volatile("s_waitcnt vmcnt(0)" ::: "memory");
        __builtin_amdgcn_s_barrier();
        RD_B(0, 0);
        RD_A(0, 0, 0);
        mfma16(0);
        RD_A(0, 0, 4);
        mfma16(4);
    }

    // Epilogue: per-wave LDS bounce -> full-128B-line stores (R13-verified).
    __builtin_amdgcn_s_barrier();
    {
        char* eb = lds + wid * 2048;
        const int rloc = (lane >> 4) * 4;
        const int g = lane >> 4;
        const int orow0 = row0 + wm * 128;
        const int ocol0 = col0 + wn * 64;
        float bcol[4];
        #pragma unroll
        for (int nf = 0; nf < 4; ++nf) bcol[nf] = bias[ocol0 + nf * 16 + r15];
        const int rdrow = lane >> 3;
        const int rdcolb = (lane & 7) * 16;
        const int rdoff0 = rdrow * 128 + (rdcolb ^ ((rdrow >> 2) << 5));
        const int rdoff1 = (rdrow + 8) * 128 + (rdcolb ^ (((rdrow + 8) >> 2) << 5));
        bf16_t* outbase = outp + (size_t)ocol0 + (lane & 7) * 8;
        #pragma unroll
        for (int mf = 0; mf < 8; ++mf) {
            #pragma unroll
            for (int i = 0; i < 4; ++i) {
                const int r = rloc + i;
                #pragma unroll
                for (int nf = 0; nf < 4; ++nf) {
                    const float v = fmaxf(acc[mf][nf][i] + bcol[nf], 0.f);
                    *(bf16_t*)(eb + r * 128 + ((nf ^ g) * 32 + r15 * 2)) = (__bf16)v;
                }
            }
            __builtin_amdgcn_sched_barrier(0);
            asm volatile("" ::: "memory");
            const bf16x8 v0 = *(const bf16x8*)(eb + rdoff0);
            const bf16x8 v1 = *(const bf16x8*)(eb + rdoff1);
            asm volatile("" ::: "memory");
            __builtin_amdgcn_sched_barrier(0);
            *(bf16x8*)(outbase + (size_t)(orow0 + mf * 16 + rdrow) * N) = v0;
            *(bf16x8*)(outbase + (size_t)(orow0 + mf * 16 + 8 + rdrow) * N) = v1;
        }
    }
    #undef TILE
    #undef RD_A
    #undef RD_B
    #undef BAR
}

// ---------------- 128x128 GEMM (layer 3) with fused TW (R15-correctness-proven)
#define BM 128
#define BN 128
#define BK 32

template<bool OUT_F32, int K>
__global__ void __launch_bounds__(256) gemm_lora(
    const bf16_t* __restrict__ Abuf, const bf16_t* __restrict__ Wbuf,
    const float* __restrict__ bias, const bf16_t* __restrict__ Acat,
    const bf16_t* __restrict__ Bepi, void* __restrict__ outp,
    const int N,
    const int* __restrict__ domv, const float* __restrict__ salpha)
{
    __shared__ bf16_t lA[BM * BK];
    __shared__ bf16_t lB[BN * BK];
    __shared__ bf16_t lAc[32 * BK];
    const int t = threadIdx.x;
    const int row0 = blockIdx.y * BM;
    const int col0 = blockIdx.x * BN;
    const int wid = t >> 6, lane = t & 63;
    const int wr = wid >> 1, wc = wid & 1;
    const int ln15 = lane & 15, kg = (lane >> 4) * 8;
    const int srow = t >> 2, sg8 = (t & 3) * 8;
    const bf16_t* gA = Abuf + (size_t)(row0 + srow) * K + sg8;
    const bf16_t* gB = Wbuf + (size_t)(col0 + srow) * K + sg8;
    bf16_t* ldA  = &lA[t * 8];
    bf16_t* ldA2 = &lA[2048 + t * 8];
    bf16_t* ldB  = &lB[t * 8];
    bf16_t* ldB2 = &lB[2048 + t * 8];
    f32x4 acc[4][4] = {};
    f32x4 twacc[4] = {};
    bf16x8 af[4], bfr[4];
    const int aoff = (wr * 64 + ln15) * BK + kg;
    const int boff = (wc * 64 + ln15) * BK + kg;

    auto compute_tile = [&]() {
        #pragma unroll
        for (int m = 0; m < 4; ++m) af[m] = *(const bf16x8*)&lA[aoff + m * 16 * BK];
        #pragma unroll
        for (int n = 0; n < 4; ++n) bfr[n] = *(const bf16x8*)&lB[boff + n * 16 * BK];
        #pragma unroll
        for (int m = 0; m < 4; ++m)
            #pragma unroll
            for (int n = 0; n < 4; ++n)
                acc[m][n] = __builtin_amdgcn_mfma_f32_16x16x32_bf16(af[m], bfr[n], acc[m][n], 0, 0, 0);
    };

    constexpr size_t half = (size_t)64 * K;
    constexpr int nk = K / BK;
    #pragma unroll 1
    for (int kt = 0; kt < nk; ++kt) {
        gload_lds16(gA + kt * BK, ldA);
        gload_lds16(gA + half + kt * BK, ldA2);
        gload_lds16(gB + kt * BK, ldB);
        gload_lds16(gB + half + kt * BK, ldB2);
        if (t < 128)
            gload_lds16(Acat + (size_t)(t >> 2) * K + kt * BK + (t & 3) * 8, (char*)lAc + t * 16);
        __syncthreads();
        compute_tile();
        {
            const bf16x8 acatF = *(const bf16x8*)&lAc[(wc * 16 + ln15) * BK + kg];
            #pragma unroll
            for (int m = 0; m < 4; ++m)
                twacc[m] = __builtin_amdgcn_mfma_f32_16x16x32_bf16(af[m], acatF, twacc[m], 0, 0, 0);
        }
        __syncthreads();
    }
    // TW finalize: scale and write into lA linear [128][32]
    {
        const int i16 = lane >> 4;
        #pragma unroll
        for (int m = 0; m < 4; ++m) {
            #pragma unroll
            for (int i = 0; i < 4; ++i) {
                const int r = wr * 64 + m * 16 + i16 * 4 + i;
                const int d = domv[row0 + r];
                const int c = wc * 16 + ln15;
                const float s = salpha[(d * 3 + 2) * 4 + wc * 2 + (ln15 >> 3)];
                lA[r * BK + c] = (__bf16)(twacc[m][i] * s);
            }
        }
    }
    gload_lds16(Bepi + (size_t)(col0 + srow) * 32 + sg8, ldB);
    gload_lds16(Bepi + (size_t)(col0 + 64 + srow) * 32 + sg8, ldB2);
    __syncthreads();
    compute_tile();

    const int orow = row0 + wr * 64 + (lane >> 4) * 4;
    const int ocol = col0 + wc * 64 + ln15;
    #pragma unroll
    for (int n = 0; n < 4; ++n) {
        const int col = ocol + n * 16;
        const float bn = bias[col];
        #pragma unroll
        for (int m = 0; m < 4; ++m) {
            const int rbase = orow + m * 16;
            #pragma unroll
            for (int i = 0; i < 4; ++i) {
                const float v = fmaxf(acc[m][n][i] + bn, 0.f);
                if constexpr (OUT_F32)
                    ((float*)outp)[(size_t)(rbase + i) * N + col] = v;
                else
                    ((bf16_t*)outp)[(size_t)(rbase + i) * N + col] = (__bf16)v;
            }
        }
    }
}

extern "C" void kernel_launch(void* const* d_in, const int* in_sizes, int n_in,
                              void* d_out, int out_size, void* d_ws, size_t ws_size,
                              hipStream_t stream)
{
    const float* x    = (const float*)d_in[0];
    const int*   dom  = (const int*)d_in[1];
    const float* W1   = (const float*)d_in[2];  const float* b1  = (const float*)d_in[3];
    const float* W2   = (const float*)d_in[4];  const float* b2  = (const float*)d_in[5];
    const float* W3   = (const float*)d_in[6];  const float* b3  = (const float*)d_in[7];
    const float* A1   = (const float*)d_in[8];  const float* B1  = (const float*)d_in[9];
    const float* A2   = (const float*)d_in[10]; const float* B2  = (const float*)d_in[11];
    const float* A3   = (const float*)d_in[12]; const float* B3  = (const float*)d_in[13];
    const float* dome = (const float*)d_in[14]; const float* lpos = (const float*)d_in[15];
    const float* Wi1  = (const float*)d_in[16]; const float* bi1 = (const float*)d_in[17];
    const float* Wi2  = (const float*)d_in[18]; const float* bi2 = (const float*)d_in[19];
    const float* Wa1  = (const float*)d_in[20]; const float* ba1 = (const float*)d_in[21];
    const float* Wa2  = (const float*)d_in[22]; const float* ba2 = (const float*)d_in[23];
    const float* gate = (const float*)d_in[24]; const float* Rb  = (const float*)d_in[25];
    (void)in_sizes; (void)n_in; (void)out_size; (void)ws_size;

    constexpr int Bsz = 16384, D0 = 2048, D1 = 2048, D2 = 1024, D3 = 512;

    char* ws = (char*)d_ws;
    size_t off = 0;
    auto alloc = [&](size_t bytes) -> void* {
        void* p = ws + off;
        off = (off + bytes + 255) & ~(size_t)255;
        return p;
    };
    float*  salpha = (float*) alloc(8 * 3 * 4 * sizeof(float));
    bf16_t* W1b = (bf16_t*)alloc((size_t)D1 * D0 * 2);
    bf16_t* W2b = (bf16_t*)alloc((size_t)D2 * D1 * 2);
    bf16_t* W3b = (bf16_t*)alloc((size_t)D3 * D2 * 2);
    bf16_t* Ac1 = (bf16_t*)alloc((size_t)32 * D0 * 2);
    bf16_t* Ac2 = (bf16_t*)alloc((size_t)32 * D1 * 2);
    bf16_t* Ac3 = (bf16_t*)alloc((size_t)32 * D2 * 2);
    bf16_t* Be1 = (bf16_t*)alloc((size_t)D1 * 32 * 2);
    bf16_t* Be2 = (bf16_t*)alloc((size_t)D2 * 32 * 2);
    bf16_t* Be3 = (bf16_t*)alloc((size_t)D3 * 32 * 2);
    bf16_t* TWb = (bf16_t*)alloc((size_t)Bsz * 32 * 2);
    bf16_t* xb  = (bf16_t*)alloc((size_t)Bsz * D0 * 2);
    bf16_t* h1b = (bf16_t*)alloc((size_t)Bsz * D1 * 2);
    bf16_t* h2b = xb;  // xb dead after layer-1 GEMM

    // prep: routing (1) + W/A cvt (6816) + Bepi (448) + x cast (16384)
    prep_kernel<<<23649, 256, 0, stream>>>(
        dome, lpos, Wi1, bi1, Wi2, bi2, Wa1, ba1, Wa2, ba2, gate, Rb, salpha,
        W1, W2, W3, A1, A2, A3, W1b,
        B1, B2, B3, Be1,
        x, xb);

    // layer 1: K = D0 = 2048, N = D1 = 2048
    tw_kernel<<<Bsz / 64, 512, 0, stream>>>(xb, Ac1, salpha, dom, 0, D0, TWb);
    gemm_lora8<2048><<<(Bsz / 256) * (D1 / 256), 512, 0, stream>>>(xb, W1b, b1, TWb, Be1, h1b, D1, D1 / 256);
    // layer 2: K = D1 = 2048, N = D2 = 1024
    tw_kernel<<<Bsz / 64, 512, 0, stream>>>(h1b, Ac2, salpha, dom, 1, D1, TWb);
    gemm_lora8<2048><<<(Bsz / 256) * (D2 / 256), 512, 0, stream>>>(h1b, W2b, b2, TWb, Be2, h2b, D2, D2 / 256);
    // layer 3: K = D2 = 1024 (f32 out, 128^2 kernel, TW fused — low reg pressure)
    gemm_lora<true, 1024><<<dim3(D3 / BN, Bsz / BM), 256, 0, stream>>>(
        h2b, W3b, b3, Ac3, Be3, d_out, D3, dom, salpha);
}